// Round 3
// baseline (144.707 us; speedup 1.0000x reference)
//
#include <hip/hip_runtime.h>

#define EPS 1e-6f
#define LN2 0.6931471805599453f

typedef float f4 __attribute__((ext_vector_type(4)));

constexpr int B = 64;
constexpr int NPB = 512 * 512;                     // elements per batch = 262144
constexpr int BLOCKS_PER_BATCH = 16;
constexpr int NBLK = B * BLOCKS_PER_BATCH;         // 1024 blocks = 4/CU
constexpr int THREADS = 256;
constexpr int CHUNK = NPB / BLOCKS_PER_BATCH;      // 16384 elements per block
constexpr int ITERS = CHUNK / 4 / THREADS;         // 16 float4-pairs per thread

__device__ __forceinline__ float waveReduce(float v) {
    #pragma unroll
    for (int off = 32; off > 0; off >>= 1) v += __shfl_down(v, off, 64);
    return v;
}

// Fused kernel, fence-FREE cross-block handoff.
//
// Round-1 lesson: __threadfence / ACQ_REL atomics at agent scope emit
// buffer_wbl2 + buffer_inv (full per-XCD L2 writeback/invalidate). 1024 of
// them cost +75us and strangled the stream (115us vs ~25us for this loop).
//
// This version uses the hand-asm producer-consumer pattern instead — ZERO
// cache-maintenance instructions:
//   * partials stored via RELAXED/AGENT atomic stores -> global_store sc1
//     (write-through to the device-coherent point; no dirty L2 line to flush)
//   * inline s_waitcnt vmcnt(0) orders store COMPLETION before the ticket
//     (completion of an sc1 store IS cross-XCD visibility)
//   * ticket fetch_add RELAXED/AGENT — atomic RMWs are coherent at the MALL
//   * winner reads partials via RELAXED/AGENT atomic loads (sc1, cache-bypass)
//     in the exact k order of the old kl_final -> bit-identical result.
//
// Hot loop = the proven 136.5us round-0 structure (nt loads, depth-2 rotating
// register pipeline; depth-4 measured +2us — reverted).
__global__ __launch_bounds__(THREADS) void kl_fused(
        const float* __restrict__ pred, const float* __restrict__ truem,
        float* __restrict__ ws, unsigned int* __restrict__ ticket,
        float* __restrict__ out) {
    const size_t base = (size_t)blockIdx.x * CHUNK;
    const f4* p4 = (const f4*)(pred + base);
    const f4* t4 = (const f4*)(truem + base);

    float sp = 0.f, st = 0.f, s = 0.f;

    f4 pc = __builtin_nontemporal_load(&p4[threadIdx.x]);
    f4 tc = __builtin_nontemporal_load(&t4[threadIdx.x]);
    #pragma unroll
    for (int j = 1; j <= ITERS; ++j) {
        f4 pn, tn;
        if (j < ITERS) {
            pn = __builtin_nontemporal_load(&p4[threadIdx.x + j * THREADS]);
            tn = __builtin_nontemporal_load(&t4[threadIdx.x + j * THREADS]);
        }
        // consume cur while next is in flight (bit-exact baseline order)
        sp += (pc.x + pc.y) + (pc.z + pc.w);
        st += (tc.x + tc.y) + (tc.z + tc.w);
        float px = pc.x + EPS, py = pc.y + EPS, pz = pc.z + EPS, pw = pc.w + EPS;
        float tx = tc.x + EPS, ty = tc.y + EPS, tz = tc.z + EPS, tw = tc.w + EPS;
        s += tx * (__log2f(tx) - __log2f(px));
        s += ty * (__log2f(ty) - __log2f(py));
        s += tz * (__log2f(tz) - __log2f(pz));
        s += tw * (__log2f(tw) - __log2f(pw));
        pc = pn; tc = tn;
    }

    sp = waveReduce(sp);
    st = waveReduce(st);
    s  = waveReduce(s);

    __shared__ float red[3][THREADS / 64];
    __shared__ int sh_last;
    const int wave = threadIdx.x >> 6;
    const int lane = threadIdx.x & 63;
    if (lane == 0) { red[0][wave] = sp; red[1][wave] = st; red[2][wave] = s; }
    __syncthreads();
    if (threadIdx.x == 0) {
        float a0 = 0.f, a1 = 0.f, a2 = 0.f;
        #pragma unroll
        for (int w = 0; w < THREADS / 64; ++w) {
            a0 += red[0][w]; a1 += red[1][w]; a2 += red[2][w];
        }
        // write-through (sc1) stores — visible at the coherent point on
        // completion, no L2 flush required
        __hip_atomic_store(&ws[blockIdx.x], a0,
                           __ATOMIC_RELAXED, __HIP_MEMORY_SCOPE_AGENT);
        __hip_atomic_store(&ws[NBLK + blockIdx.x], a1,
                           __ATOMIC_RELAXED, __HIP_MEMORY_SCOPE_AGENT);
        __hip_atomic_store(&ws[2 * NBLK + blockIdx.x], a2,
                           __ATOMIC_RELAXED, __HIP_MEMORY_SCOPE_AGENT);
        // order: stores COMPLETE before the ticket increment issues
        asm volatile("s_waitcnt vmcnt(0)" ::: "memory");
        unsigned int t = __hip_atomic_fetch_add(
            ticket, 1u, __ATOMIC_RELAXED, __HIP_MEMORY_SCOPE_AGENT);
        sh_last = (t == (unsigned int)(NBLK - 1));
    }
    __syncthreads();
    if (!sh_last) return;

    // ---- last-arriving block: finalize. Same summation order as the old
    // kl_final -> bit-identical output (absmax 0.0). ----
    if (threadIdx.x < B) {
        const int b = threadIdx.x;        // one wave, one batch per lane
        float Sp = 0.f, St = 0.f, S = 0.f;
        #pragma unroll
        for (int k = 0; k < BLOCKS_PER_BATCH; ++k) {
            const int idx = b * BLOCKS_PER_BATCH + k;
            Sp += __hip_atomic_load(&ws[idx],
                    __ATOMIC_RELAXED, __HIP_MEMORY_SCOPE_AGENT);
            St += __hip_atomic_load(&ws[NBLK + idx],
                    __ATOMIC_RELAXED, __HIP_MEMORY_SCOPE_AGENT);
            S  += __hip_atomic_load(&ws[2 * NBLK + idx],
                    __ATOMIC_RELAXED, __HIP_MEMORY_SCOPE_AGENT);
        }
        const float epsN = (float)NPB * EPS;   // sum of the per-element +EPS
        Sp += epsN;
        St += epsN;
        float kl = (S * LN2) / St + logf(Sp / St);
        kl = waveReduce(kl);
        if (b == 0) out[0] = kl * (1.0f / B);
    }
}

extern "C" void kernel_launch(void* const* d_in, const int* in_sizes, int n_in,
                              void* d_out, int out_size, void* d_ws, size_t ws_size,
                              hipStream_t stream) {
    const float* pred  = (const float*)d_in[0];
    const float* truem = (const float*)d_in[1];
    float* out = (float*)d_out;
    float* ws  = (float*)d_ws;
    unsigned int* ticket = (unsigned int*)(ws + 3 * NBLK);

    // ws is re-poisoned by the harness each iteration: ticket must be zeroed.
    // 4-byte stream-ordered memset, graph-capture safe.
    hipMemsetAsync(ticket, 0, sizeof(unsigned int), stream);
    kl_fused<<<NBLK, THREADS, 0, stream>>>(pred, truem, ws, ticket, out);
}